// Round 9
// baseline (227.977 us; speedup 1.0000x reference)
//
#include <hip/hip_runtime.h>
#include <hip/hip_fp16.h>

constexpr int NV  = 4096;
constexpr int DIN = 256;
constexpr int DH  = 64;
constexpr int NH  = 8;
constexpr int K2  = 512;
constexpr int Z2  = 16;    // layer-2 j-split

typedef _Float16 half8 __attribute__((ext_vector_type(8)));
typedef float f32x4 __attribute__((ext_vector_type(4)));
typedef unsigned u32x4 __attribute__((ext_vector_type(4)));

__device__ __forceinline__ unsigned fkey(float x) {
    unsigned b = __float_as_uint(x);
    return b ^ ((unsigned)((int)b >> 31) | 0x80000000u);
}
__device__ __forceinline__ float fkey_inv(unsigned key) {
    unsigned b = (key & 0x80000000u) ? (key ^ 0x80000000u) : ~key;
    return __uint_as_float(b);
}

// keys layout: [0..7] maxkey l1 heads, [8] maxkey l2, [16..271] mt1[h][32], [272..303] mt2[32]
constexpr int NKEYS = 304;

// ---------------- prep (+adjmask merged) ----------------
__global__ void prep_kernel(const float* __restrict__ feat,
                            const int* __restrict__ adj,
                            const float* __restrict__ Wh,
                            const float* __restrict__ ah,
                            const float* __restrict__ Wout,
                            const float* __restrict__ aout,
                            _Float16* __restrict__ xf16,
                            _Float16* __restrict__ WTh,
                            _Float16* __restrict__ WTo,
                            float* __restrict__ aLR,
                            unsigned* __restrict__ keys,
                            unsigned long long* __restrict__ mask)
{
    if (blockIdx.x < NV) {
        int row = blockIdx.x;
        int wave = threadIdx.x >> 6, lane = threadIdx.x & 63;
        for (int g = wave; g < 64; g += 4) {
            int v = adj[(size_t)row*NV + g*64 + lane];
            unsigned long long b = __ballot(v > 0);
            if (lane == 0) mask[(size_t)row*64 + g] = b;
        }
        return;
    }
    int tid = (blockIdx.x - NV) * blockDim.x + threadIdx.x;
    int nth = 256 * 256;
    for (int i = tid; i < NV*DIN; i += nth) xf16[i] = (_Float16)feat[i];
    for (int i = tid; i < NH*DH*DIN; i += nth) {
        int h = i >> 14, n = (i >> 8) & 63, k = i & 255;
        WTh[i] = (_Float16)Wh[(h*DIN + k)*DH + n];
    }
    for (int i = tid; i < DH*K2; i += nth) {
        int n = i >> 9, k = i & 511;
        WTo[i] = (_Float16)Wout[k*DH + n];
    }
    for (int i = tid; i < NH*DH; i += nth) {
        int h = i >> 6, j = i & 63;
        aLR[i]          = ah[h*128 + j];
        aLR[NH*DH + i]  = ah[h*128 + 64 + j];
    }
    for (int i = tid; i < DH; i += nth) {
        aLR[2*NH*DH + i]      = aout[i];
        aLR[2*NH*DH + DH + i] = aout[64 + i];
    }
    if (tid < NKEYS) keys[tid] = 0u;
}

// ---------------- GEMM layer1 ----------------
template<int K>
__global__ __launch_bounds__(256) void gemm_kernel(
    const _Float16* __restrict__ A,
    const _Float16* __restrict__ WT,
    const float* __restrict__ aL,
    const float* __restrict__ aR,
    _Float16* __restrict__ hT,
    float* __restrict__ hl,
    float* __restrict__ hr,
    unsigned* __restrict__ maxkey,
    unsigned* __restrict__ mtkey)
{
    const int head = blockIdx.y;
    const int i0 = blockIdx.x * 64;
    const int t = threadIdx.x;
    const int wave = t >> 6, lane = t & 63, m = lane & 15, q = lane >> 4;

    const _Float16* Ap = A + (size_t)(i0 + wave*16 + m) * K + q*8;
    const _Float16* Wp = WT + (size_t)head*DH*K + (size_t)m*K + q*8;

    f32x4 acc0 = {0.f,0.f,0.f,0.f}, acc1 = acc0, acc2 = acc0, acc3 = acc0;
    for (int k0 = 0; k0 < K; k0 += 32) {
        half8 a  = *(const half8*)(Ap + k0);
        half8 b0 = *(const half8*)(Wp + k0);
        half8 b1 = *(const half8*)(Wp + 16*K + k0);
        half8 b2 = *(const half8*)(Wp + 32*K + k0);
        half8 b3 = *(const half8*)(Wp + 48*K + k0);
        acc0 = __builtin_amdgcn_mfma_f32_16x16x32_f16(a, b0, acc0, 0, 0, 0);
        acc1 = __builtin_amdgcn_mfma_f32_16x16x32_f16(a, b1, acc1, 0, 0, 0);
        acc2 = __builtin_amdgcn_mfma_f32_16x16x32_f16(a, b2, acc2, 0, 0, 0);
        acc3 = __builtin_amdgcn_mfma_f32_16x16x32_f16(a, b3, acc3, 0, 0, 0);
    }

    __shared__ _Float16 T[64][80];
    const int rb = wave*16 + q*4;
    for (int r = 0; r < 4; r++) {
        T[ 0 + m][rb + r] = (_Float16)acc0[r];
        T[16 + m][rb + r] = (_Float16)acc1[r];
        T[32 + m][rb + r] = (_Float16)acc2[r];
        T[48 + m][rb + r] = (_Float16)acc3[r];
    }
    __syncthreads();

    {
        int d = t >> 2, seg = t & 3;
        half8* dst = (half8*)(hT + (size_t)(head*DH + d)*NV + i0 + seg*16);
        dst[0] = *(const half8*)&T[d][seg*16];
        dst[1] = *(const half8*)&T[d][seg*16 + 8];
    }
    __shared__ float red[2][4][64];
    {
        int il = t & 63, part = t >> 6;
        float sl = 0.f, sr = 0.f;
        for (int kk = 0; kk < 16; kk++) {
            int k = part*16 + kk;
            float hv = (float)T[k][il];
            sl += hv * aL[head*DH + k];
            sr += hv * aR[head*DH + k];
        }
        red[0][part][il] = sl;
        red[1][part][il] = sr;
    }
    __syncthreads();
    if (t < 64) {
        float sl = red[0][0][t] + red[0][1][t] + red[0][2][t] + red[0][3][t];
        float sr = red[1][0][t] + red[1][1][t] + red[1][2][t] + red[1][3][t];
        hl[head*NV + i0 + t] = sl;
        hr[head*NV + i0 + t] = sr;
        unsigned key = fkey(sr);
        for (int off = 32; off > 0; off >>= 1) {
            unsigned o = __shfl_xor(key, off);
            key = key > o ? key : o;
        }
        if (t == 0) {
            atomicMax(maxkey + head, key);
            atomicMax(mtkey + head*32 + (i0 >> 7), key);
        }
    }
}

// ---------------- GEMM layer2 ----------------
__global__ __launch_bounds__(256) void gemm2_kernel(
    const _Float16* __restrict__ A,
    const _Float16* __restrict__ WT,
    const float* __restrict__ aL,
    const float* __restrict__ aR,
    _Float16* __restrict__ hT,
    float* __restrict__ hl,
    float* __restrict__ hr,
    unsigned* __restrict__ maxkey,
    unsigned* __restrict__ mtkey)
{
    const int i0 = blockIdx.x * 16;
    const int t = threadIdx.x;
    const int w = t >> 6, lane = t & 63, m = lane & 15, q = lane >> 4;

    const _Float16* Ap = A + (size_t)(i0 + m)*K2 + w*128 + q*8;
    const _Float16* Wp = WT + (size_t)m*K2 + w*128 + q*8;

    f32x4 zero4 = {0.f,0.f,0.f,0.f};
    f32x4 acc[4] = {zero4, zero4, zero4, zero4};
    #pragma unroll
    for (int k0 = 0; k0 < 128; k0 += 32) {
        half8 a = *(const half8*)(Ap + k0);
        #pragma unroll
        for (int nt = 0; nt < 4; nt++) {
            half8 b = *(const half8*)(Wp + (size_t)nt*16*K2 + k0);
            acc[nt] = __builtin_amdgcn_mfma_f32_16x16x32_f16(a, b, acc[nt], 0, 0, 0);
        }
    }

    __shared__ float Cred[4][16][68];
    #pragma unroll
    for (int r = 0; r < 4; r++)
        #pragma unroll
        for (int nt = 0; nt < 4; nt++)
            Cred[w][q*4 + r][nt*16 + m] = acc[nt][r];
    __syncthreads();

    const int col = t & 63, r0 = (t >> 6) * 4;
    #pragma unroll
    for (int rr = 0; rr < 4; rr++) {
        int row = r0 + rr;
        float s = Cred[0][row][col] + Cred[1][row][col]
                + Cred[2][row][col] + Cred[3][row][col];
        hT[(size_t)col*NV + i0 + row] = (_Float16)s;
        Cred[0][row][col] = s;
    }
    __syncthreads();
    if (t < 16) {
        float sl = 0.f, sr = 0.f;
        for (int c = 0; c < 64; c++) {
            float v = Cred[0][t][c];
            sl += v * aL[c];
            sr += v * aR[c];
        }
        hl[i0 + t] = sl;
        hr[i0 + t] = sr;
        unsigned key = fkey(sr);
        atomicMax(maxkey, key);
        atomicMax(mtkey + (i0 >> 7), key);
    }
}

// ---------------- exp-free fused masked-softmax attention ----------------
// p_ij = max(e1_i*F_j, e2_i*G_j) & mask; fp16 partial outputs; l via ones-MFMA.
template<int MODE, int NMT>
__global__ __launch_bounds__(256, 3) void att_kernel(
    const _Float16* __restrict__ hT,
    const float* __restrict__ hl,
    const float* __restrict__ hr,
    const unsigned* __restrict__ maxkey,
    const unsigned* __restrict__ mtkey,
    const unsigned* __restrict__ adjm32,
    _Float16* __restrict__ accz,
    float* __restrict__ lz)
{
    const int head = (MODE == 0) ? blockIdx.y : 0;
    const int i0 = blockIdx.x * (NMT*64);
    const int t = threadIdx.x;
    const int wave = t >> 6, lane = t & 63, m = lane & 15, q = lane >> 4;

    __shared__ _Float16 BT[64][152];   // 76-word stride: only free m<->m+8 bank aliasing
    __shared__ __align__(16) _Float16 Fs[128], Gs[128];
    __shared__ __align__(16) unsigned mask_s[NMT*64][4];
    __shared__ float b1_s[NMT*64], b2_s[NMT*64];

    const float L2E = 1.4426950408889634f;
    const float maxhr = fkey_inv(*maxkey);

    if (t < NMT*64) {
        float v = hl[head*NV + i0 + t];
        float X = v + maxhr;
        float mm = fmaxf(X, 0.2f*X) * L2E;
        b1_s[t] = __builtin_amdgcn_exp2f(v*L2E - mm);
        b2_s[t] = __builtin_amdgcn_exp2f(0.2f*L2E*v - mm);
    }
    __syncthreads();

    float b1r[NMT], b2r[NMT];
    #pragma unroll
    for (int mt = 0; mt < NMT; mt++) {
        int row = wave*(NMT*16) + mt*16 + m;
        b1r[mt] = b1_s[row];
        b2r[mt] = b2_s[row];
    }

    f32x4 zero4 = {0.f,0.f,0.f,0.f};
    f32x4 acc[NMT][4];
    f32x4 accl[NMT];
    #pragma unroll
    for (int mt = 0; mt < NMT; mt++) {
        accl[mt] = zero4;
        #pragma unroll
        for (int nt = 0; nt < 4; nt++) acc[mt][nt] = zero4;
    }
    half8 ones;
    #pragma unroll
    for (int u = 0; u < 8; u++) ones[u] = (_Float16)1.0f;

    const int ntiles = 32 / gridDim.z;
    const int tile0  = blockIdx.z * ntiles;

    for (int tt = 0; tt < ntiles; tt++) {
        const int j0 = (tile0 + tt) * 128;
        #pragma unroll
        for (int ii = 0; ii < 4; ii++) {
            int d = (t >> 4) + ii*16;
            *(half8*)&BT[d][(t & 15)*8] =
                *(const half8*)(hT + (size_t)(head*DH + d)*NV + j0 + (t & 15)*8);
        }
        const float mtv = fkey_inv(mtkey[(MODE == 0 ? head*32 : 0) + (j0 >> 7)]);
        if (t < 128) {
            float d = (hr[head*NV + j0 + t] - mtv) * L2E;   // <= 0
            Fs[t] = (_Float16)__builtin_amdgcn_exp2f(d);
            Gs[t] = (_Float16)__builtin_amdgcn_exp2f(0.2f*d);
        }
        if (t < NMT*64)
            *(u32x4*)&mask_s[t][0] = *(const u32x4*)&adjm32[(size_t)(i0 + t)*128 + (j0 >> 5)];
        __syncthreads();

        const float s1 = __builtin_amdgcn_exp2f(mtv * L2E);
        const float s2 = __builtin_amdgcn_exp2f(0.2f * mtv * L2E);
        half8 e1v[NMT], e2v[NMT];
        u32x4 mkv[NMT];
        #pragma unroll
        for (int mt = 0; mt < NMT; mt++) {
            _Float16 e1 = (_Float16)(b1r[mt] * s1);
            _Float16 e2 = (_Float16)(b2r[mt] * s2);
            #pragma unroll
            for (int u = 0; u < 8; u++) { e1v[mt][u] = e1; e2v[mt][u] = e2; }
            mkv[mt] = *(const u32x4*)&mask_s[wave*(NMT*16) + mt*16 + m][0];
        }

        #pragma unroll
        for (int ks = 0; ks < 4; ks++) {
            const int jj = ks*32 + q*8;
            half8 F8 = *(const half8*)&Fs[jj];
            half8 G8 = *(const half8*)&Gs[jj];
            half8 b0 = *(const half8*)&BT[ 0 + m][jj];
            half8 b1 = *(const half8*)&BT[16 + m][jj];
            half8 b2 = *(const half8*)&BT[32 + m][jj];
            half8 b3 = *(const half8*)&BT[48 + m][jj];
            #pragma unroll
            for (int mt = 0; mt < NMT; mt++) {
                const unsigned mk8 = (mkv[mt][ks] >> (q*8)) & 0xffu;
                half8 t1 = e1v[mt] * F8;
                half8 t2 = e2v[mt] * G8;
                half8 am = __builtin_elementwise_max(t1, t2);
                u32x4 av = __builtin_bit_cast(u32x4, am);
                #pragma unroll
                for (int pp = 0; pp < 4; pp++) {
                    unsigned mw = ((0u - ((mk8 >> (2*pp)) & 1u)) & 0x0000FFFFu)
                                | ((0u - ((mk8 >> (2*pp+1)) & 1u)) & 0xFFFF0000u);
                    av[pp] &= mw;
                }
                half8 a = __builtin_bit_cast(half8, av);
                acc[mt][0] = __builtin_amdgcn_mfma_f32_16x16x32_f16(a, b0, acc[mt][0], 0, 0, 0);
                acc[mt][1] = __builtin_amdgcn_mfma_f32_16x16x32_f16(a, b1, acc[mt][1], 0, 0, 0);
                acc[mt][2] = __builtin_amdgcn_mfma_f32_16x16x32_f16(a, b2, acc[mt][2], 0, 0, 0);
                acc[mt][3] = __builtin_amdgcn_mfma_f32_16x16x32_f16(a, b3, acc[mt][3], 0, 0, 0);
                accl[mt]   = __builtin_amdgcn_mfma_f32_16x16x32_f16(a, ones, accl[mt], 0, 0, 0);
            }
        }
        __syncthreads();
    }

    #pragma unroll
    for (int mt = 0; mt < NMT; mt++) {
        #pragma unroll
        for (int r = 0; r < 4; r++) {
            const int i = i0 + wave*(NMT*16) + mt*16 + q*4 + r;
            if (MODE == 0) {
                _Float16* dst = accz + ((size_t)blockIdx.z*NV + i)*K2 + head*DH;
                #pragma unroll
                for (int nt = 0; nt < 4; nt++) dst[nt*16 + m] = (_Float16)acc[mt][nt][r];
                if (m == 0) lz[((size_t)blockIdx.z*NH + head)*NV + i] = accl[mt][r];
            } else {
                _Float16* dst = accz + ((size_t)blockIdx.z*NV + i)*DH;
                #pragma unroll
                for (int nt = 0; nt < 4; nt++) dst[nt*16 + m] = (_Float16)acc[mt][nt][r];
                if (m == 0) lz[(size_t)blockIdx.z*NV + i] = accl[mt][r];
            }
        }
    }
}

// ---------------- combine layer-1 partials -> x2 fp16 with ELU ----------------
__global__ void combine_x2_kernel(const _Float16* __restrict__ accz,
                                  const float* __restrict__ lz,
                                  _Float16* __restrict__ x2, int Z1)
{
    const float L2E = 1.4426950408889634f;
    int idx = blockIdx.x * blockDim.x + threadIdx.x;
    int i = idx >> 9, h = (idx & 511) >> 6;
    float s = 0.f, l = 0.f;
    for (int z = 0; z < Z1; z++) {
        s += (float)accz[(size_t)z*NV*K2 + idx];
        l += lz[((size_t)z*NH + h)*NV + i];
    }
    float v = l > 0.f ? s / l : 0.f;
    v = v > 0.f ? v : (__builtin_amdgcn_exp2f(v * L2E) - 1.f);
    x2[idx] = (_Float16)v;
}

// ---------------- finalize layer-2 ----------------
__global__ void finalize_kernel(const _Float16* __restrict__ accz,
                                const float* __restrict__ lz,
                                float* __restrict__ out)
{
    int idx = blockIdx.x * blockDim.x + threadIdx.x;
    int i = idx >> 6;
    float s = 0.f, l = 0.f;
    #pragma unroll
    for (int z = 0; z < Z2; z++) {
        s += (float)accz[(size_t)z*NV*DH + idx];
        l += lz[(size_t)z*NV + i];
    }
    out[idx] = l > 0.f ? s / l : 0.f;
}

extern "C" void kernel_launch(void* const* d_in, const int* in_sizes, int n_in,
                              void* d_out, int out_size, void* d_ws, size_t ws_size,
                              hipStream_t stream)
{
    const float* feat = (const float*)d_in[0];
    const int* adj    = (const int*)d_in[1];
    const float* Wh   = (const float*)d_in[2];
    const float* ah   = (const float*)d_in[3];
    const float* Wout = (const float*)d_in[4];
    const float* aout = (const float*)d_in[5];

    char* p = (char*)d_ws;
    auto alloc = [&](size_t bytes) { char* r = p; p += (bytes + 255) & ~255ull; return r; };

    _Float16* xf16 = (_Float16*)alloc((size_t)NV*DIN*2);
    _Float16* WTh  = (_Float16*)alloc((size_t)NH*DH*DIN*2);
    _Float16* WTo  = (_Float16*)alloc((size_t)DH*K2*2);
    float*    aLR  = (float*)alloc((2*NH*DH + 2*DH)*4);
    unsigned* keys = (unsigned*)alloc(NKEYS*4);
    unsigned long long* adjm = (unsigned long long*)alloc((size_t)NV*64*8);
    _Float16* hT1 = (_Float16*)alloc((size_t)NH*DH*NV*2);
    float* hl1 = (float*)alloc((size_t)NH*NV*4);
    float* hr1 = (float*)alloc((size_t)NH*NV*4);
    _Float16* x2  = (_Float16*)alloc((size_t)NV*K2*2);
    _Float16* hT2 = (_Float16*)alloc((size_t)DH*NV*2);
    _Float16* acc2z = (_Float16*)alloc((size_t)Z2*NV*DH*2);
    float* l2z   = (float*)alloc((size_t)Z2*NV*4);
    float* hl2 = (float*)alloc(NV*4);
    float* hr2 = (float*)alloc(NV*4);

    size_t used = (size_t)(p - (char*)d_ws);
    size_t per_z = (size_t)NV*K2*2 + (size_t)NH*NV*4 + 512;
    size_t avail = ws_size > used ? ws_size - used : 0;
    int Z1 = (avail >= 8*per_z + 4096) ? 8 : 4;
    _Float16* acc1z = (_Float16*)alloc((size_t)Z1*NV*K2*2);   // layout [z][NV][K2]
    float* l1z   = (float*)alloc((size_t)Z1*NH*NV*4);

    unsigned* maxkey = keys;
    unsigned* mtk1   = keys + 16;
    unsigned* mtk2   = keys + 272;

    prep_kernel<<<NV + 256, 256, 0, stream>>>(feat, adj, Wh, ah, Wout, aout,
                                              xf16, WTh, WTo, aLR, keys, adjm);
    gemm_kernel<DIN><<<dim3(64, NH), 256, 0, stream>>>(xf16, WTh, aLR, aLR + NH*DH,
                                                       hT1, hl1, hr1, maxkey, mtk1);
    att_kernel<0, 4><<<dim3(NV/256, NH, Z1), 256, 0, stream>>>(
        hT1, hl1, hr1, maxkey, mtk1, (const unsigned*)adjm, acc1z, l1z);
    combine_x2_kernel<<<dim3(NV*K2/256), 256, 0, stream>>>(acc1z, l1z, x2, Z1);
    gemm2_kernel<<<dim3(NV/16), 256, 0, stream>>>(x2, WTo, aLR + 2*NH*DH, aLR + 2*NH*DH + DH,
                                                  hT2, hl2, hr2, maxkey + 8, mtk2);
    att_kernel<1, 2><<<dim3(NV/128, 1, Z2), 256, 0, stream>>>(
        hT2, hl2, hr2, maxkey + 8, mtk2, (const unsigned*)adjm, acc2z, l2z);
    finalize_kernel<<<dim3(NV*DH/256), 256, 0, stream>>>(acc2z, l2z, (float*)d_out);
}

// Round 10
// 199.743 us; speedup vs baseline: 1.1414x; 1.1414x over previous
//
#include <hip/hip_runtime.h>
#include <hip/hip_fp16.h>

constexpr int NV  = 4096;
constexpr int DIN = 256;
constexpr int DH  = 64;
constexpr int NH  = 8;
constexpr int K2  = 512;
constexpr int Z2  = 8;     // layer-2 j-split

typedef _Float16 half8 __attribute__((ext_vector_type(8)));
typedef float f32x4 __attribute__((ext_vector_type(4)));
typedef unsigned u32x4 __attribute__((ext_vector_type(4)));

__device__ __forceinline__ unsigned fkey(float x) {
    unsigned b = __float_as_uint(x);
    return b ^ ((unsigned)((int)b >> 31) | 0x80000000u);
}
__device__ __forceinline__ float fkey_inv(unsigned key) {
    unsigned b = (key & 0x80000000u) ? (key ^ 0x80000000u) : ~key;
    return __uint_as_float(b);
}

// keys layout: [0..7] maxkey l1 heads, [8] maxkey l2, [16..271] mt1[h][32], [272..303] mt2[32]
constexpr int NKEYS = 304;

// ---------------- prep (+adjmask merged) ----------------
__global__ void prep_kernel(const float* __restrict__ feat,
                            const int* __restrict__ adj,
                            const float* __restrict__ Wh,
                            const float* __restrict__ ah,
                            const float* __restrict__ Wout,
                            const float* __restrict__ aout,
                            _Float16* __restrict__ xf16,
                            _Float16* __restrict__ WTh,
                            _Float16* __restrict__ WTo,
                            float* __restrict__ aLR,
                            unsigned* __restrict__ keys,
                            unsigned long long* __restrict__ mask)
{
    if (blockIdx.x < NV) {
        int row = blockIdx.x;
        int wave = threadIdx.x >> 6, lane = threadIdx.x & 63;
        for (int g = wave; g < 64; g += 4) {
            int v = adj[(size_t)row*NV + g*64 + lane];
            unsigned long long b = __ballot(v > 0);
            if (lane == 0) mask[(size_t)row*64 + g] = b;
        }
        return;
    }
    int tid = (blockIdx.x - NV) * blockDim.x + threadIdx.x;
    int nth = 256 * 256;
    for (int i = tid; i < NV*DIN; i += nth) xf16[i] = (_Float16)feat[i];
    for (int i = tid; i < NH*DH*DIN; i += nth) {
        int h = i >> 14, n = (i >> 8) & 63, k = i & 255;
        WTh[i] = (_Float16)Wh[(h*DIN + k)*DH + n];
    }
    for (int i = tid; i < DH*K2; i += nth) {
        int n = i >> 9, k = i & 511;
        WTo[i] = (_Float16)Wout[k*DH + n];
    }
    for (int i = tid; i < NH*DH; i += nth) {
        int h = i >> 6, j = i & 63;
        aLR[i]          = ah[h*128 + j];
        aLR[NH*DH + i]  = ah[h*128 + 64 + j];
    }
    for (int i = tid; i < DH; i += nth) {
        aLR[2*NH*DH + i]      = aout[i];
        aLR[2*NH*DH + DH + i] = aout[64 + i];
    }
    if (tid < NKEYS) keys[tid] = 0u;
}

// ---------------- GEMM layer1 ----------------
template<int K>
__global__ __launch_bounds__(256) void gemm_kernel(
    const _Float16* __restrict__ A,
    const _Float16* __restrict__ WT,
    const float* __restrict__ aL,
    const float* __restrict__ aR,
    _Float16* __restrict__ hT,
    float* __restrict__ hl,
    float* __restrict__ hr,
    unsigned* __restrict__ maxkey,
    unsigned* __restrict__ mtkey)
{
    const int head = blockIdx.y;
    const int i0 = blockIdx.x * 64;
    const int t = threadIdx.x;
    const int wave = t >> 6, lane = t & 63, m = lane & 15, q = lane >> 4;

    const _Float16* Ap = A + (size_t)(i0 + wave*16 + m) * K + q*8;
    const _Float16* Wp = WT + (size_t)head*DH*K + (size_t)m*K + q*8;

    f32x4 acc0 = {0.f,0.f,0.f,0.f}, acc1 = acc0, acc2 = acc0, acc3 = acc0;
    for (int k0 = 0; k0 < K; k0 += 32) {
        half8 a  = *(const half8*)(Ap + k0);
        half8 b0 = *(const half8*)(Wp + k0);
        half8 b1 = *(const half8*)(Wp + 16*K + k0);
        half8 b2 = *(const half8*)(Wp + 32*K + k0);
        half8 b3 = *(const half8*)(Wp + 48*K + k0);
        acc0 = __builtin_amdgcn_mfma_f32_16x16x32_f16(a, b0, acc0, 0, 0, 0);
        acc1 = __builtin_amdgcn_mfma_f32_16x16x32_f16(a, b1, acc1, 0, 0, 0);
        acc2 = __builtin_amdgcn_mfma_f32_16x16x32_f16(a, b2, acc2, 0, 0, 0);
        acc3 = __builtin_amdgcn_mfma_f32_16x16x32_f16(a, b3, acc3, 0, 0, 0);
    }

    __shared__ _Float16 T[64][80];
    const int rb = wave*16 + q*4;
    for (int r = 0; r < 4; r++) {
        T[ 0 + m][rb + r] = (_Float16)acc0[r];
        T[16 + m][rb + r] = (_Float16)acc1[r];
        T[32 + m][rb + r] = (_Float16)acc2[r];
        T[48 + m][rb + r] = (_Float16)acc3[r];
    }
    __syncthreads();

    {
        int d = t >> 2, seg = t & 3;
        half8* dst = (half8*)(hT + (size_t)(head*DH + d)*NV + i0 + seg*16);
        dst[0] = *(const half8*)&T[d][seg*16];
        dst[1] = *(const half8*)&T[d][seg*16 + 8];
    }
    __shared__ float red[2][4][64];
    {
        int il = t & 63, part = t >> 6;
        float sl = 0.f, sr = 0.f;
        for (int kk = 0; kk < 16; kk++) {
            int k = part*16 + kk;
            float hv = (float)T[k][il];
            sl += hv * aL[head*DH + k];
            sr += hv * aR[head*DH + k];
        }
        red[0][part][il] = sl;
        red[1][part][il] = sr;
    }
    __syncthreads();
    if (t < 64) {
        float sl = red[0][0][t] + red[0][1][t] + red[0][2][t] + red[0][3][t];
        float sr = red[1][0][t] + red[1][1][t] + red[1][2][t] + red[1][3][t];
        hl[head*NV + i0 + t] = sl;
        hr[head*NV + i0 + t] = sr;
        unsigned key = fkey(sr);
        for (int off = 32; off > 0; off >>= 1) {
            unsigned o = __shfl_xor(key, off);
            key = key > o ? key : o;
        }
        if (t == 0) {
            atomicMax(maxkey + head, key);
            atomicMax(mtkey + head*32 + (i0 >> 7), key);
        }
    }
}

// ---------------- GEMM layer2 ----------------
__global__ __launch_bounds__(256) void gemm2_kernel(
    const _Float16* __restrict__ A,
    const _Float16* __restrict__ WT,
    const float* __restrict__ aL,
    const float* __restrict__ aR,
    _Float16* __restrict__ hT,
    float* __restrict__ hl,
    float* __restrict__ hr,
    unsigned* __restrict__ maxkey,
    unsigned* __restrict__ mtkey)
{
    const int i0 = blockIdx.x * 16;
    const int t = threadIdx.x;
    const int w = t >> 6, lane = t & 63, m = lane & 15, q = lane >> 4;

    const _Float16* Ap = A + (size_t)(i0 + m)*K2 + w*128 + q*8;
    const _Float16* Wp = WT + (size_t)m*K2 + w*128 + q*8;

    f32x4 zero4 = {0.f,0.f,0.f,0.f};
    f32x4 acc[4] = {zero4, zero4, zero4, zero4};
    #pragma unroll
    for (int k0 = 0; k0 < 128; k0 += 32) {
        half8 a = *(const half8*)(Ap + k0);
        #pragma unroll
        for (int nt = 0; nt < 4; nt++) {
            half8 b = *(const half8*)(Wp + (size_t)nt*16*K2 + k0);
            acc[nt] = __builtin_amdgcn_mfma_f32_16x16x32_f16(a, b, acc[nt], 0, 0, 0);
        }
    }

    __shared__ float Cred[4][16][68];
    #pragma unroll
    for (int r = 0; r < 4; r++)
        #pragma unroll
        for (int nt = 0; nt < 4; nt++)
            Cred[w][q*4 + r][nt*16 + m] = acc[nt][r];
    __syncthreads();

    const int col = t & 63, r0 = (t >> 6) * 4;
    #pragma unroll
    for (int rr = 0; rr < 4; rr++) {
        int row = r0 + rr;
        float s = Cred[0][row][col] + Cred[1][row][col]
                + Cred[2][row][col] + Cred[3][row][col];
        hT[(size_t)col*NV + i0 + row] = (_Float16)s;
        Cred[0][row][col] = s;
    }
    __syncthreads();
    if (t < 16) {
        float sl = 0.f, sr = 0.f;
        for (int c = 0; c < 64; c++) {
            float v = Cred[0][t][c];
            sl += v * aL[c];
            sr += v * aR[c];
        }
        hl[i0 + t] = sl;
        hr[i0 + t] = sr;
        unsigned key = fkey(sr);
        atomicMax(maxkey, key);
        atomicMax(mtkey + (i0 >> 7), key);
    }
}

// ---------------- exp-free fused masked-softmax attention ----------------
// p_ij = max(e1_i*F_j, e2_i*G_j) & mask; fp32 partial outputs; l via ones-MFMA.
template<int MODE, int NMT>
__global__ __launch_bounds__(256, 4) void att_kernel(
    const _Float16* __restrict__ hT,
    const float* __restrict__ hl,
    const float* __restrict__ hr,
    const unsigned* __restrict__ maxkey,
    const unsigned* __restrict__ mtkey,
    const unsigned* __restrict__ adjm32,
    float* __restrict__ accz,
    float* __restrict__ lz)
{
    const int head = (MODE == 0) ? blockIdx.y : 0;
    const int i0 = blockIdx.x * (NMT*64);
    const int t = threadIdx.x;
    const int wave = t >> 6, lane = t & 63, m = lane & 15, q = lane >> 4;

    __shared__ _Float16 BT[64][136];
    __shared__ __align__(16) _Float16 Fs[128], Gs[128];
    __shared__ __align__(16) unsigned mask_s[NMT*64][4];
    __shared__ float b1_s[NMT*64], b2_s[NMT*64];

    const float L2E = 1.4426950408889634f;
    const float maxhr = fkey_inv(*maxkey);

    if (t < NMT*64) {
        float v = hl[head*NV + i0 + t];
        float X = v + maxhr;
        float mm = fmaxf(X, 0.2f*X) * L2E;
        b1_s[t] = __builtin_amdgcn_exp2f(v*L2E - mm);
        b2_s[t] = __builtin_amdgcn_exp2f(0.2f*L2E*v - mm);
    }
    __syncthreads();

    float b1r[NMT], b2r[NMT];
    #pragma unroll
    for (int mt = 0; mt < NMT; mt++) {
        int row = wave*(NMT*16) + mt*16 + m;
        b1r[mt] = b1_s[row];
        b2r[mt] = b2_s[row];
    }

    f32x4 zero4 = {0.f,0.f,0.f,0.f};
    f32x4 acc[NMT][4];
    f32x4 accl[NMT];
    #pragma unroll
    for (int mt = 0; mt < NMT; mt++) {
        accl[mt] = zero4;
        #pragma unroll
        for (int nt = 0; nt < 4; nt++) acc[mt][nt] = zero4;
    }
    half8 ones;
    #pragma unroll
    for (int u = 0; u < 8; u++) ones[u] = (_Float16)1.0f;

    const int ntiles = 32 / gridDim.z;
    const int tile0  = blockIdx.z * ntiles;

    for (int tt = 0; tt < ntiles; tt++) {
        const int j0 = (tile0 + tt) * 128;
        #pragma unroll
        for (int ii = 0; ii < 4; ii++) {
            int d = (t >> 4) + ii*16;
            *(half8*)&BT[d][(t & 15)*8] =
                *(const half8*)(hT + (size_t)(head*DH + d)*NV + j0 + (t & 15)*8);
        }
        const float mtv = fkey_inv(mtkey[(MODE == 0 ? head*32 : 0) + (j0 >> 7)]);
        if (t < 128) {
            float d = (hr[head*NV + j0 + t] - mtv) * L2E;   // <= 0
            Fs[t] = (_Float16)__builtin_amdgcn_exp2f(d);
            Gs[t] = (_Float16)__builtin_amdgcn_exp2f(0.2f*d);
        }
        if (t < NMT*64)
            *(u32x4*)&mask_s[t][0] = *(const u32x4*)&adjm32[(size_t)(i0 + t)*128 + (j0 >> 5)];
        __syncthreads();

        const float s1 = __builtin_amdgcn_exp2f(mtv * L2E);
        const float s2 = __builtin_amdgcn_exp2f(0.2f * mtv * L2E);
        half8 e1v[NMT], e2v[NMT];
        u32x4 mkv[NMT];
        #pragma unroll
        for (int mt = 0; mt < NMT; mt++) {
            _Float16 e1 = (_Float16)(b1r[mt] * s1);
            _Float16 e2 = (_Float16)(b2r[mt] * s2);
            #pragma unroll
            for (int u = 0; u < 8; u++) { e1v[mt][u] = e1; e2v[mt][u] = e2; }
            mkv[mt] = *(const u32x4*)&mask_s[wave*(NMT*16) + mt*16 + m][0];
        }

        #pragma unroll
        for (int ks = 0; ks < 4; ks++) {
            const int jj = ks*32 + q*8;
            half8 F8 = *(const half8*)&Fs[jj];
            half8 G8 = *(const half8*)&Gs[jj];
            half8 b0 = *(const half8*)&BT[ 0 + m][jj];
            half8 b1 = *(const half8*)&BT[16 + m][jj];
            half8 b2 = *(const half8*)&BT[32 + m][jj];
            half8 b3 = *(const half8*)&BT[48 + m][jj];
            #pragma unroll
            for (int mt = 0; mt < NMT; mt++) {
                const unsigned mk8 = (mkv[mt][ks] >> (q*8)) & 0xffu;
                half8 t1 = e1v[mt] * F8;
                half8 t2 = e2v[mt] * G8;
                half8 am = __builtin_elementwise_max(t1, t2);
                u32x4 av = __builtin_bit_cast(u32x4, am);
                #pragma unroll
                for (int pp = 0; pp < 4; pp++) {
                    unsigned mw = ((0u - ((mk8 >> (2*pp)) & 1u)) & 0x0000FFFFu)
                                | ((0u - ((mk8 >> (2*pp+1)) & 1u)) & 0xFFFF0000u);
                    av[pp] &= mw;
                }
                half8 a = __builtin_bit_cast(half8, av);
                acc[mt][0] = __builtin_amdgcn_mfma_f32_16x16x32_f16(a, b0, acc[mt][0], 0, 0, 0);
                acc[mt][1] = __builtin_amdgcn_mfma_f32_16x16x32_f16(a, b1, acc[mt][1], 0, 0, 0);
                acc[mt][2] = __builtin_amdgcn_mfma_f32_16x16x32_f16(a, b2, acc[mt][2], 0, 0, 0);
                acc[mt][3] = __builtin_amdgcn_mfma_f32_16x16x32_f16(a, b3, acc[mt][3], 0, 0, 0);
                accl[mt]   = __builtin_amdgcn_mfma_f32_16x16x32_f16(a, ones, accl[mt], 0, 0, 0);
            }
        }
        __syncthreads();
    }

    #pragma unroll
    for (int mt = 0; mt < NMT; mt++) {
        #pragma unroll
        for (int r = 0; r < 4; r++) {
            const int i = i0 + wave*(NMT*16) + mt*16 + q*4 + r;
            if (MODE == 0) {
                float* dst = accz + ((size_t)blockIdx.z*NV + i)*K2 + head*DH;
                #pragma unroll
                for (int nt = 0; nt < 4; nt++) dst[nt*16 + m] = acc[mt][nt][r];
                if (m == 0) lz[((size_t)blockIdx.z*NH + head)*NV + i] = accl[mt][r];
            } else {
                float* dst = accz + ((size_t)blockIdx.z*NV + i)*DH;
                #pragma unroll
                for (int nt = 0; nt < 4; nt++) dst[nt*16 + m] = acc[mt][nt][r];
                if (m == 0) lz[(size_t)blockIdx.z*NV + i] = accl[mt][r];
            }
        }
    }
}

// ---------------- combine layer-1 partials -> x2 fp16 with ELU ----------------
__global__ void combine_x2_kernel(const float* __restrict__ accz,
                                  const float* __restrict__ lz,
                                  _Float16* __restrict__ x2, int Z1)
{
    const float L2E = 1.4426950408889634f;
    int idx = blockIdx.x * blockDim.x + threadIdx.x;
    int i = idx >> 9, h = (idx & 511) >> 6;
    float s = 0.f, l = 0.f;
    for (int z = 0; z < Z1; z++) {
        s += accz[(size_t)z*NV*K2 + idx];
        l += lz[((size_t)z*NH + h)*NV + i];
    }
    float v = l > 0.f ? s / l : 0.f;
    v = v > 0.f ? v : (__builtin_amdgcn_exp2f(v * L2E) - 1.f);
    x2[idx] = (_Float16)v;
}

// ---------------- finalize layer-2 ----------------
__global__ void finalize_kernel(const float* __restrict__ accz,
                                const float* __restrict__ lz,
                                float* __restrict__ out)
{
    int idx = blockIdx.x * blockDim.x + threadIdx.x;
    int i = idx >> 6;
    float s = 0.f, l = 0.f;
    #pragma unroll
    for (int z = 0; z < Z2; z++) {
        s += accz[(size_t)z*NV*DH + idx];
        l += lz[(size_t)z*NV + i];
    }
    out[idx] = l > 0.f ? s / l : 0.f;
}

extern "C" void kernel_launch(void* const* d_in, const int* in_sizes, int n_in,
                              void* d_out, int out_size, void* d_ws, size_t ws_size,
                              hipStream_t stream)
{
    const float* feat = (const float*)d_in[0];
    const int* adj    = (const int*)d_in[1];
    const float* Wh   = (const float*)d_in[2];
    const float* ah   = (const float*)d_in[3];
    const float* Wout = (const float*)d_in[4];
    const float* aout = (const float*)d_in[5];

    char* p = (char*)d_ws;
    auto alloc = [&](size_t bytes) { char* r = p; p += (bytes + 255) & ~255ull; return r; };

    _Float16* xf16 = (_Float16*)alloc((size_t)NV*DIN*2);
    _Float16* WTh  = (_Float16*)alloc((size_t)NH*DH*DIN*2);
    _Float16* WTo  = (_Float16*)alloc((size_t)DH*K2*2);
    float*    aLR  = (float*)alloc((2*NH*DH + 2*DH)*4);
    unsigned* keys = (unsigned*)alloc(NKEYS*4);
    unsigned long long* adjm = (unsigned long long*)alloc((size_t)NV*64*8);
    _Float16* hT1 = (_Float16*)alloc((size_t)NH*DH*NV*2);
    float* hl1 = (float*)alloc((size_t)NH*NV*4);
    float* hr1 = (float*)alloc((size_t)NH*NV*4);
    _Float16* x2  = (_Float16*)alloc((size_t)NV*K2*2);
    _Float16* hT2 = (_Float16*)alloc((size_t)DH*NV*2);
    float* acc2z = (float*)alloc((size_t)Z2*NV*DH*4);
    float* l2z   = (float*)alloc((size_t)Z2*NV*4);
    float* hl2 = (float*)alloc(NV*4);
    float* hr2 = (float*)alloc(NV*4);

    size_t used = (size_t)(p - (char*)d_ws);
    size_t per_z = (size_t)NV*K2*4 + (size_t)NH*NV*4 + 512;
    size_t avail = ws_size > used ? ws_size - used : 0;
    int Z1 = (avail >= 4*per_z + 4096) ? 4 : 2;
    float* acc1z = (float*)alloc((size_t)Z1*NV*K2*4);
    float* l1z   = (float*)alloc((size_t)Z1*NH*NV*4);

    unsigned* maxkey = keys;
    unsigned* mtk1   = keys + 16;
    unsigned* mtk2   = keys + 272;

    prep_kernel<<<NV + 256, 256, 0, stream>>>(feat, adj, Wh, ah, Wout, aout,
                                              xf16, WTh, WTo, aLR, keys, adjm);
    gemm_kernel<DIN><<<dim3(64, NH), 256, 0, stream>>>(xf16, WTh, aLR, aLR + NH*DH,
                                                       hT1, hl1, hr1, maxkey, mtk1);
    att_kernel<0, 2><<<dim3(NV/128, NH, Z1), 256, 0, stream>>>(
        hT1, hl1, hr1, maxkey, mtk1, (const unsigned*)adjm, acc1z, l1z);
    combine_x2_kernel<<<dim3(NV*K2/256), 256, 0, stream>>>(acc1z, l1z, x2, Z1);
    gemm2_kernel<<<dim3(NV/16), 256, 0, stream>>>(x2, WTo, aLR + 2*NH*DH, aLR + 2*NH*DH + DH,
                                                  hT2, hl2, hr2, maxkey + 8, mtk2);
    att_kernel<1, 1><<<dim3(NV/64, 1, Z2), 256, 0, stream>>>(
        hT2, hl2, hr2, maxkey + 8, mtk2, (const unsigned*)adjm, acc2z, l2z);
    finalize_kernel<<<dim3(NV*DH/256), 256, 0, stream>>>(acc2z, l2z, (float*)d_out);
}

// Round 11
// 196.976 us; speedup vs baseline: 1.1574x; 1.0140x over previous
//
#include <hip/hip_runtime.h>
#include <hip/hip_fp16.h>

constexpr int NV  = 4096;
constexpr int DIN = 256;
constexpr int DH  = 64;
constexpr int NH  = 8;
constexpr int K2  = 512;
constexpr int Z2  = 8;     // layer-2 j-split

typedef _Float16 half8 __attribute__((ext_vector_type(8)));
typedef float f32x4 __attribute__((ext_vector_type(4)));
typedef unsigned u32x4 __attribute__((ext_vector_type(4)));

__device__ __forceinline__ unsigned fkey(float x) {
    unsigned b = __float_as_uint(x);
    return b ^ ((unsigned)((int)b >> 31) | 0x80000000u);
}
__device__ __forceinline__ float fkey_inv(unsigned key) {
    unsigned b = (key & 0x80000000u) ? (key ^ 0x80000000u) : ~key;
    return __uint_as_float(b);
}

// keys layout: [0..7] maxkey l1 heads, [8] maxkey l2, [16..271] mt1[h][32], [272..303] mt2[32]
constexpr int NKEYS = 304;

// ---------------- prep (+adjmask merged) ----------------
__global__ void prep_kernel(const float* __restrict__ feat,
                            const int* __restrict__ adj,
                            const float* __restrict__ Wh,
                            const float* __restrict__ ah,
                            const float* __restrict__ Wout,
                            const float* __restrict__ aout,
                            _Float16* __restrict__ xf16,
                            _Float16* __restrict__ WTh,
                            _Float16* __restrict__ WTo,
                            float* __restrict__ aLR,
                            unsigned* __restrict__ keys,
                            unsigned long long* __restrict__ mask)
{
    if (blockIdx.x < NV) {
        int row = blockIdx.x;
        int wave = threadIdx.x >> 6, lane = threadIdx.x & 63;
        for (int g = wave; g < 64; g += 4) {
            int v = adj[(size_t)row*NV + g*64 + lane];
            unsigned long long b = __ballot(v > 0);
            if (lane == 0) mask[(size_t)row*64 + g] = b;
        }
        return;
    }
    int tid = (blockIdx.x - NV) * blockDim.x + threadIdx.x;
    int nth = 256 * 256;
    for (int i = tid; i < NV*DIN; i += nth) xf16[i] = (_Float16)feat[i];
    for (int i = tid; i < NH*DH*DIN; i += nth) {
        int h = i >> 14, n = (i >> 8) & 63, k = i & 255;
        WTh[i] = (_Float16)Wh[(h*DIN + k)*DH + n];
    }
    for (int i = tid; i < DH*K2; i += nth) {
        int n = i >> 9, k = i & 511;
        WTo[i] = (_Float16)Wout[k*DH + n];
    }
    for (int i = tid; i < NH*DH; i += nth) {
        int h = i >> 6, j = i & 63;
        aLR[i]          = ah[h*128 + j];
        aLR[NH*DH + i]  = ah[h*128 + 64 + j];
    }
    for (int i = tid; i < DH; i += nth) {
        aLR[2*NH*DH + i]      = aout[i];
        aLR[2*NH*DH + DH + i] = aout[64 + i];
    }
    if (tid < NKEYS) keys[tid] = 0u;
}

// ---------------- GEMM layer1 ----------------
template<int K>
__global__ __launch_bounds__(256) void gemm_kernel(
    const _Float16* __restrict__ A,
    const _Float16* __restrict__ WT,
    const float* __restrict__ aL,
    const float* __restrict__ aR,
    _Float16* __restrict__ hT,
    float* __restrict__ hl,
    float* __restrict__ hr,
    unsigned* __restrict__ maxkey,
    unsigned* __restrict__ mtkey)
{
    const int head = blockIdx.y;
    const int i0 = blockIdx.x * 64;
    const int t = threadIdx.x;
    const int wave = t >> 6, lane = t & 63, m = lane & 15, q = lane >> 4;

    const _Float16* Ap = A + (size_t)(i0 + wave*16 + m) * K + q*8;
    const _Float16* Wp = WT + (size_t)head*DH*K + (size_t)m*K + q*8;

    f32x4 acc0 = {0.f,0.f,0.f,0.f}, acc1 = acc0, acc2 = acc0, acc3 = acc0;
    for (int k0 = 0; k0 < K; k0 += 32) {
        half8 a  = *(const half8*)(Ap + k0);
        half8 b0 = *(const half8*)(Wp + k0);
        half8 b1 = *(const half8*)(Wp + 16*K + k0);
        half8 b2 = *(const half8*)(Wp + 32*K + k0);
        half8 b3 = *(const half8*)(Wp + 48*K + k0);
        acc0 = __builtin_amdgcn_mfma_f32_16x16x32_f16(a, b0, acc0, 0, 0, 0);
        acc1 = __builtin_amdgcn_mfma_f32_16x16x32_f16(a, b1, acc1, 0, 0, 0);
        acc2 = __builtin_amdgcn_mfma_f32_16x16x32_f16(a, b2, acc2, 0, 0, 0);
        acc3 = __builtin_amdgcn_mfma_f32_16x16x32_f16(a, b3, acc3, 0, 0, 0);
    }

    __shared__ _Float16 T[64][80];
    const int rb = wave*16 + q*4;
    for (int r = 0; r < 4; r++) {
        T[ 0 + m][rb + r] = (_Float16)acc0[r];
        T[16 + m][rb + r] = (_Float16)acc1[r];
        T[32 + m][rb + r] = (_Float16)acc2[r];
        T[48 + m][rb + r] = (_Float16)acc3[r];
    }
    __syncthreads();

    {
        int d = t >> 2, seg = t & 3;
        half8* dst = (half8*)(hT + (size_t)(head*DH + d)*NV + i0 + seg*16);
        dst[0] = *(const half8*)&T[d][seg*16];
        dst[1] = *(const half8*)&T[d][seg*16 + 8];
    }
    __shared__ float red[2][4][64];
    {
        int il = t & 63, part = t >> 6;
        float sl = 0.f, sr = 0.f;
        for (int kk = 0; kk < 16; kk++) {
            int k = part*16 + kk;
            float hv = (float)T[k][il];
            sl += hv * aL[head*DH + k];
            sr += hv * aR[head*DH + k];
        }
        red[0][part][il] = sl;
        red[1][part][il] = sr;
    }
    __syncthreads();
    if (t < 64) {
        float sl = red[0][0][t] + red[0][1][t] + red[0][2][t] + red[0][3][t];
        float sr = red[1][0][t] + red[1][1][t] + red[1][2][t] + red[1][3][t];
        hl[head*NV + i0 + t] = sl;
        hr[head*NV + i0 + t] = sr;
        unsigned key = fkey(sr);
        for (int off = 32; off > 0; off >>= 1) {
            unsigned o = __shfl_xor(key, off);
            key = key > o ? key : o;
        }
        if (t == 0) {
            atomicMax(maxkey + head, key);
            atomicMax(mtkey + head*32 + (i0 >> 7), key);
        }
    }
}

// ---------------- GEMM layer2 ----------------
__global__ __launch_bounds__(256) void gemm2_kernel(
    const _Float16* __restrict__ A,
    const _Float16* __restrict__ WT,
    const float* __restrict__ aL,
    const float* __restrict__ aR,
    _Float16* __restrict__ hT,
    float* __restrict__ hl,
    float* __restrict__ hr,
    unsigned* __restrict__ maxkey,
    unsigned* __restrict__ mtkey)
{
    const int i0 = blockIdx.x * 16;
    const int t = threadIdx.x;
    const int w = t >> 6, lane = t & 63, m = lane & 15, q = lane >> 4;

    const _Float16* Ap = A + (size_t)(i0 + m)*K2 + w*128 + q*8;
    const _Float16* Wp = WT + (size_t)m*K2 + w*128 + q*8;

    f32x4 zero4 = {0.f,0.f,0.f,0.f};
    f32x4 acc[4] = {zero4, zero4, zero4, zero4};
    #pragma unroll
    for (int k0 = 0; k0 < 128; k0 += 32) {
        half8 a = *(const half8*)(Ap + k0);
        #pragma unroll
        for (int nt = 0; nt < 4; nt++) {
            half8 b = *(const half8*)(Wp + (size_t)nt*16*K2 + k0);
            acc[nt] = __builtin_amdgcn_mfma_f32_16x16x32_f16(a, b, acc[nt], 0, 0, 0);
        }
    }

    __shared__ float Cred[4][16][68];
    #pragma unroll
    for (int r = 0; r < 4; r++)
        #pragma unroll
        for (int nt = 0; nt < 4; nt++)
            Cred[w][q*4 + r][nt*16 + m] = acc[nt][r];
    __syncthreads();

    const int col = t & 63, r0 = (t >> 6) * 4;
    #pragma unroll
    for (int rr = 0; rr < 4; rr++) {
        int row = r0 + rr;
        float s = Cred[0][row][col] + Cred[1][row][col]
                + Cred[2][row][col] + Cred[3][row][col];
        hT[(size_t)col*NV + i0 + row] = (_Float16)s;
        Cred[0][row][col] = s;
    }
    __syncthreads();
    if (t < 16) {
        float sl = 0.f, sr = 0.f;
        for (int c = 0; c < 64; c++) {
            float v = Cred[0][t][c];
            sl += v * aL[c];
            sr += v * aR[c];
        }
        hl[i0 + t] = sl;
        hr[i0 + t] = sr;
        unsigned key = fkey(sr);
        atomicMax(maxkey, key);
        atomicMax(mtkey + (i0 >> 7), key);
    }
}

// ---------------- exp-free fused masked-softmax attention ----------------
// p_ij = max(e1_i*F_j, e2_i*G_j) & mask; fp16 partial outputs; l via ones-MFMA.
template<int MODE, int NMT>
__global__ __launch_bounds__(256, 4) void att_kernel(
    const _Float16* __restrict__ hT,
    const float* __restrict__ hl,
    const float* __restrict__ hr,
    const unsigned* __restrict__ maxkey,
    const unsigned* __restrict__ mtkey,
    const unsigned* __restrict__ adjm32,
    _Float16* __restrict__ accz,
    float* __restrict__ lz)
{
    const int head = (MODE == 0) ? blockIdx.y : 0;
    const int i0 = blockIdx.x * (NMT*64);
    const int t = threadIdx.x;
    const int wave = t >> 6, lane = t & 63, m = lane & 15, q = lane >> 4;

    __shared__ _Float16 BT[64][136];
    __shared__ __align__(16) _Float16 Fs[128], Gs[128];
    __shared__ __align__(16) unsigned mask_s[NMT*64][4];
    __shared__ float b1_s[NMT*64], b2_s[NMT*64];

    const float L2E = 1.4426950408889634f;
    const float maxhr = fkey_inv(*maxkey);

    if (t < NMT*64) {
        float v = hl[head*NV + i0 + t];
        float X = v + maxhr;
        float mm = fmaxf(X, 0.2f*X) * L2E;
        b1_s[t] = __builtin_amdgcn_exp2f(v*L2E - mm);
        b2_s[t] = __builtin_amdgcn_exp2f(0.2f*L2E*v - mm);
    }
    __syncthreads();

    float b1r[NMT], b2r[NMT];
    #pragma unroll
    for (int mt = 0; mt < NMT; mt++) {
        int row = wave*(NMT*16) + mt*16 + m;
        b1r[mt] = b1_s[row];
        b2r[mt] = b2_s[row];
    }

    f32x4 zero4 = {0.f,0.f,0.f,0.f};
    f32x4 acc[NMT][4];
    f32x4 accl[NMT];
    #pragma unroll
    for (int mt = 0; mt < NMT; mt++) {
        accl[mt] = zero4;
        #pragma unroll
        for (int nt = 0; nt < 4; nt++) acc[mt][nt] = zero4;
    }
    half8 ones;
    #pragma unroll
    for (int u = 0; u < 8; u++) ones[u] = (_Float16)1.0f;

    const int ntiles = 32 / gridDim.z;
    const int tile0  = blockIdx.z * ntiles;

    for (int tt = 0; tt < ntiles; tt++) {
        const int j0 = (tile0 + tt) * 128;
        #pragma unroll
        for (int ii = 0; ii < 4; ii++) {
            int d = (t >> 4) + ii*16;
            *(half8*)&BT[d][(t & 15)*8] =
                *(const half8*)(hT + (size_t)(head*DH + d)*NV + j0 + (t & 15)*8);
        }
        const float mtv = fkey_inv(mtkey[(MODE == 0 ? head*32 : 0) + (j0 >> 7)]);
        if (t < 128) {
            float d = (hr[head*NV + j0 + t] - mtv) * L2E;   // <= 0
            Fs[t] = (_Float16)__builtin_amdgcn_exp2f(d);
            Gs[t] = (_Float16)__builtin_amdgcn_exp2f(0.2f*d);
        }
        if (t < NMT*64)
            *(u32x4*)&mask_s[t][0] = *(const u32x4*)&adjm32[(size_t)(i0 + t)*128 + (j0 >> 5)];
        __syncthreads();

        const float s1 = __builtin_amdgcn_exp2f(mtv * L2E);
        const float s2 = __builtin_amdgcn_exp2f(0.2f * mtv * L2E);
        half8 e1v[NMT], e2v[NMT];
        u32x4 mkv[NMT];
        #pragma unroll
        for (int mt = 0; mt < NMT; mt++) {
            _Float16 e1 = (_Float16)(b1r[mt] * s1);
            _Float16 e2 = (_Float16)(b2r[mt] * s2);
            #pragma unroll
            for (int u = 0; u < 8; u++) { e1v[mt][u] = e1; e2v[mt][u] = e2; }
            mkv[mt] = *(const u32x4*)&mask_s[wave*(NMT*16) + mt*16 + m][0];
        }

        #pragma unroll
        for (int ks = 0; ks < 4; ks++) {
            const int jj = ks*32 + q*8;
            half8 F8 = *(const half8*)&Fs[jj];
            half8 G8 = *(const half8*)&Gs[jj];
            half8 b0 = *(const half8*)&BT[ 0 + m][jj];
            half8 b1 = *(const half8*)&BT[16 + m][jj];
            half8 b2 = *(const half8*)&BT[32 + m][jj];
            half8 b3 = *(const half8*)&BT[48 + m][jj];
            #pragma unroll
            for (int mt = 0; mt < NMT; mt++) {
                const unsigned mk8 = (mkv[mt][ks] >> (q*8)) & 0xffu;
                half8 t1 = e1v[mt] * F8;
                half8 t2 = e2v[mt] * G8;
                half8 am = __builtin_elementwise_max(t1, t2);
                u32x4 av = __builtin_bit_cast(u32x4, am);
                #pragma unroll
                for (int pp = 0; pp < 4; pp++) {
                    unsigned mw = ((0u - ((mk8 >> (2*pp)) & 1u)) & 0x0000FFFFu)
                                | ((0u - ((mk8 >> (2*pp+1)) & 1u)) & 0xFFFF0000u);
                    av[pp] &= mw;
                }
                half8 a = __builtin_bit_cast(half8, av);
                acc[mt][0] = __builtin_amdgcn_mfma_f32_16x16x32_f16(a, b0, acc[mt][0], 0, 0, 0);
                acc[mt][1] = __builtin_amdgcn_mfma_f32_16x16x32_f16(a, b1, acc[mt][1], 0, 0, 0);
                acc[mt][2] = __builtin_amdgcn_mfma_f32_16x16x32_f16(a, b2, acc[mt][2], 0, 0, 0);
                acc[mt][3] = __builtin_amdgcn_mfma_f32_16x16x32_f16(a, b3, acc[mt][3], 0, 0, 0);
                accl[mt]   = __builtin_amdgcn_mfma_f32_16x16x32_f16(a, ones, accl[mt], 0, 0, 0);
            }
        }
        __syncthreads();
    }

    #pragma unroll
    for (int mt = 0; mt < NMT; mt++) {
        #pragma unroll
        for (int r = 0; r < 4; r++) {
            const int i = i0 + wave*(NMT*16) + mt*16 + q*4 + r;
            if (MODE == 0) {
                _Float16* dst = accz + ((size_t)blockIdx.z*NV + i)*K2 + head*DH;
                #pragma unroll
                for (int nt = 0; nt < 4; nt++) dst[nt*16 + m] = (_Float16)acc[mt][nt][r];
                if (m == 0) lz[((size_t)blockIdx.z*NH + head)*NV + i] = accl[mt][r];
            } else {
                _Float16* dst = accz + ((size_t)blockIdx.z*NV + i)*DH;
                #pragma unroll
                for (int nt = 0; nt < 4; nt++) dst[nt*16 + m] = (_Float16)acc[mt][nt][r];
                if (m == 0) lz[(size_t)blockIdx.z*NV + i] = accl[mt][r];
            }
        }
    }
}

// ---------------- combine layer-1 partials -> x2 fp16 with ELU ----------------
__global__ void combine_x2_kernel(const _Float16* __restrict__ accz,
                                  const float* __restrict__ lz,
                                  _Float16* __restrict__ x2, int Z1)
{
    const float L2E = 1.4426950408889634f;
    int idx = blockIdx.x * blockDim.x + threadIdx.x;
    int i = idx >> 9, h = (idx & 511) >> 6;
    float s = 0.f, l = 0.f;
    for (int z = 0; z < Z1; z++) {
        s += (float)accz[(size_t)z*NV*K2 + idx];
        l += lz[((size_t)z*NH + h)*NV + i];
    }
    float v = l > 0.f ? s / l : 0.f;
    v = v > 0.f ? v : (__builtin_amdgcn_exp2f(v * L2E) - 1.f);
    x2[idx] = (_Float16)v;
}

// ---------------- finalize layer-2 ----------------
__global__ void finalize_kernel(const _Float16* __restrict__ accz,
                                const float* __restrict__ lz,
                                float* __restrict__ out)
{
    int idx = blockIdx.x * blockDim.x + threadIdx.x;
    int i = idx >> 6;
    float s = 0.f, l = 0.f;
    #pragma unroll
    for (int z = 0; z < Z2; z++) {
        s += (float)accz[(size_t)z*NV*DH + idx];
        l += lz[(size_t)z*NV + i];
    }
    out[idx] = l > 0.f ? s / l : 0.f;
}

extern "C" void kernel_launch(void* const* d_in, const int* in_sizes, int n_in,
                              void* d_out, int out_size, void* d_ws, size_t ws_size,
                              hipStream_t stream)
{
    const float* feat = (const float*)d_in[0];
    const int* adj    = (const int*)d_in[1];
    const float* Wh   = (const float*)d_in[2];
    const float* ah   = (const float*)d_in[3];
    const float* Wout = (const float*)d_in[4];
    const float* aout = (const float*)d_in[5];

    char* p = (char*)d_ws;
    auto alloc = [&](size_t bytes) { char* r = p; p += (bytes + 255) & ~255ull; return r; };

    _Float16* xf16 = (_Float16*)alloc((size_t)NV*DIN*2);
    _Float16* WTh  = (_Float16*)alloc((size_t)NH*DH*DIN*2);
    _Float16* WTo  = (_Float16*)alloc((size_t)DH*K2*2);
    float*    aLR  = (float*)alloc((2*NH*DH + 2*DH)*4);
    unsigned* keys = (unsigned*)alloc(NKEYS*4);
    unsigned long long* adjm = (unsigned long long*)alloc((size_t)NV*64*8);
    _Float16* hT1 = (_Float16*)alloc((size_t)NH*DH*NV*2);
    float* hl1 = (float*)alloc((size_t)NH*NV*4);
    float* hr1 = (float*)alloc((size_t)NH*NV*4);
    _Float16* x2  = (_Float16*)alloc((size_t)NV*K2*2);
    _Float16* hT2 = (_Float16*)alloc((size_t)DH*NV*2);
    _Float16* acc2z = (_Float16*)alloc((size_t)Z2*NV*DH*2);
    float* l2z   = (float*)alloc((size_t)Z2*NV*4);
    float* hl2 = (float*)alloc(NV*4);
    float* hr2 = (float*)alloc(NV*4);

    size_t used = (size_t)(p - (char*)d_ws);
    size_t per_z = (size_t)NV*K2*2 + (size_t)NH*NV*4 + 512;
    size_t avail = ws_size > used ? ws_size - used : 0;
    int Z1 = (avail >= 4*per_z + 4096) ? 4 : 2;
    _Float16* acc1z = (_Float16*)alloc((size_t)Z1*NV*K2*2);
    float* l1z   = (float*)alloc((size_t)Z1*NH*NV*4);

    unsigned* maxkey = keys;
    unsigned* mtk1   = keys + 16;
    unsigned* mtk2   = keys + 272;

    prep_kernel<<<NV + 256, 256, 0, stream>>>(feat, adj, Wh, ah, Wout, aout,
                                              xf16, WTh, WTo, aLR, keys, adjm);
    gemm_kernel<DIN><<<dim3(64, NH), 256, 0, stream>>>(xf16, WTh, aLR, aLR + NH*DH,
                                                       hT1, hl1, hr1, maxkey, mtk1);
    att_kernel<0, 2><<<dim3(NV/128, NH, Z1), 256, 0, stream>>>(
        hT1, hl1, hr1, maxkey, mtk1, (const unsigned*)adjm, acc1z, l1z);
    combine_x2_kernel<<<dim3(NV*K2/256), 256, 0, stream>>>(acc1z, l1z, x2, Z1);
    gemm2_kernel<<<dim3(NV/16), 256, 0, stream>>>(x2, WTo, aLR + 2*NH*DH, aLR + 2*NH*DH + DH,
                                                  hT2, hl2, hr2, maxkey + 8, mtk2);
    att_kernel<1, 1><<<dim3(NV/64, 1, Z2), 256, 0, stream>>>(
        hT2, hl2, hr2, maxkey + 8, mtk2, (const unsigned*)adjm, acc2z, l2z);
    finalize_kernel<<<dim3(NV*DH/256), 256, 0, stream>>>(acc2z, l2z, (float*)d_out);
}